// Round 5
// baseline (613.257 us; speedup 1.0000x reference)
//
#include <hip/hip_runtime.h>
#include <math.h>

#define S_LEN 2048
#define DMODEL 4096
#define NHQ 32
#define NHKV 8
#define HD 128
#define DQ 4096
#define DKV 1024
#define NQKV 6144   // 4096 q + 1024 k + 1024 v

typedef __attribute__((ext_vector_type(8))) short bf16x8;
typedef __attribute__((ext_vector_type(4))) float f32x4;
typedef __attribute__((ext_vector_type(8))) unsigned short u16x8;

__device__ __forceinline__ unsigned short f2bf(float f) {
    unsigned u = __builtin_bit_cast(unsigned, f);
    u += 0x7fffu + ((u >> 16) & 1u);     // round-to-nearest-even
    return (unsigned short)(u >> 16);
}

__device__ __forceinline__ void gload16(const void* g, void* l) {
    __builtin_amdgcn_global_load_lds(
        (const __attribute__((address_space(1))) unsigned int*)g,
        (__attribute__((address_space(3))) unsigned int*)l, 16, 0, 0);
}

// ---------------------------------------------------------------------------
// fp32 -> bf16 bulk convert (8 elems/thread/iter)
// ---------------------------------------------------------------------------
__global__ __launch_bounds__(256) void cvt_bf16(const float* __restrict__ src,
                                                unsigned short* __restrict__ dst, int n8)
{
    for (int i = blockIdx.x * 256 + threadIdx.x; i < n8; i += gridDim.x * 256) {
        const float4 a = ((const float4*)src)[2 * i];
        const float4 b = ((const float4*)src)[2 * i + 1];
        u16x8 o;
        o[0] = f2bf(a.x); o[1] = f2bf(a.y); o[2] = f2bf(a.z); o[3] = f2bf(a.w);
        o[4] = f2bf(b.x); o[5] = f2bf(b.y); o[6] = f2bf(b.z); o[7] = f2bf(b.w);
        ((u16x8*)dst)[i] = o;
    }
}

// ---------------------------------------------------------------------------
// bf16 MFMA GEMM, ring-4 counted-vmcnt pipeline (T3/T4 on the m97 skeleton).
// C[M,N] = A[M,K]*B[N,K]^T fp32. 128x128 tile, BK=32, 4 waves, 4x4 frags.
// 4 LDS slots (64KB, 2 blocks/CU); iteration t stages tile t+3 and waits
// vmcnt(12) so 3 tiles of global_load_lds stay in flight ACROSS barriers
// (raw s_barrier, no vmcnt(0) drain — the m97 structural stall).
// T1 bijective XCD swizzle on the flat block id (nwg % 8 == 0 required).
// ---------------------------------------------------------------------------
#define BBM 128
#define BBN 128
#define BBK 32

__global__ __launch_bounds__(256) void gemm_bf16(const unsigned short* __restrict__ A,
                                                 const unsigned short* __restrict__ B,
                                                 float* __restrict__ C,
                                                 int M, int N, int K)
{
    __shared__ __align__(16) unsigned short As[4][BBM * BBK];  // 4 x 8KB
    __shared__ __align__(16) unsigned short Bs[4][BBN * BBK];  // 4 x 8KB

    const int tid  = threadIdx.x;
    const int lane = tid & 63;
    const int w    = tid >> 6;
    const int wy   = w >> 1, wx = w & 1;

    // XCD-aware swizzle: XCD k gets a contiguous chunk of logical blocks.
    const int gX  = gridDim.x;
    const int nwg = gX * gridDim.y;
    int id = blockIdx.y * gX + blockIdx.x;
    id = (id & 7) * (nwg >> 3) + (id >> 3);
    const int bm = (id / gX) * BBM, bn = (id % gX) * BBN;

    const int l15 = lane & 15;
    const int lk16 = (lane >> 4) * 16;
    const int ldsWaveBase = (tid & 192) * 16;

    f32x4 acc[4][4];
    #pragma unroll
    for (int m = 0; m < 4; ++m)
        #pragma unroll
        for (int n = 0; n < 4; ++n) acc[m][n] = (f32x4){0.f, 0.f, 0.f, 0.f};

    const char* Ab = (const char*)A;
    const char* Bb = (const char*)B;
    const int NT = K / BBK;   // 128 for K=4096

    auto STAGE = [&](int slot, int t) {
        #pragma unroll
        for (int c = 0; c < 2; ++c) {
            const int i = tid + c * 256;
            const int r = i >> 2;
            const int co = (i & 3) << 4;
            gload16(Ab + ((size_t)(bm + r) * K + t * BBK) * 2 + co,
                    (char*)As + slot * 8192 + ldsWaveBase + c * 4096);
            gload16(Bb + ((size_t)(bn + r) * K + t * BBK) * 2 + co,
                    (char*)Bs + slot * 8192 + ldsWaveBase + c * 4096);
        }
    };

    STAGE(0, 0); STAGE(1, 1); STAGE(2, 2);   // 12 loads/thread in flight

    for (int t = 0; t < NT; ++t) {
        // B1: all waves done READING slot (t+3)&3 (== (t-1)&3, read last iter).
        __builtin_amdgcn_sched_barrier(0);
        asm volatile("s_waitcnt lgkmcnt(0)" ::: "memory");
        __builtin_amdgcn_s_barrier();        // raw: no vmcnt drain
        __builtin_amdgcn_sched_barrier(0);

        const int ts = t + 3;
        if (ts < NT) STAGE(ts & 3, ts);

        // counted wait: tile t's 4 loads complete; up to 12 newer stay in flight
        const int rem = NT - 1 - t;
        if (rem >= 3)      asm volatile("s_waitcnt vmcnt(12)" ::: "memory");
        else if (rem == 2) asm volatile("s_waitcnt vmcnt(8)"  ::: "memory");
        else if (rem == 1) asm volatile("s_waitcnt vmcnt(4)"  ::: "memory");
        else               asm volatile("s_waitcnt vmcnt(0)"  ::: "memory");
        __builtin_amdgcn_sched_barrier(0);
        __builtin_amdgcn_s_barrier();        // B2: tile t visible block-wide
        __builtin_amdgcn_sched_barrier(0);

        const char* Asl = (const char*)As + (t & 3) * 8192;
        const char* Bsl = (const char*)Bs + (t & 3) * 8192;
        bf16x8 af[4], bfr[4];
        #pragma unroll
        for (int m = 0; m < 4; ++m)
            af[m] = *(const bf16x8*)(Asl + (wy * 64 + m * 16 + l15) * 64 + lk16);
        #pragma unroll
        for (int n = 0; n < 4; ++n)
            bfr[n] = *(const bf16x8*)(Bsl + (wx * 64 + n * 16 + l15) * 64 + lk16);
        __builtin_amdgcn_s_setprio(1);
        #pragma unroll
        for (int m = 0; m < 4; ++m)
            #pragma unroll
            for (int n = 0; n < 4; ++n)
                acc[m][n] = __builtin_amdgcn_mfma_f32_16x16x32_bf16(af[m], bfr[n], acc[m][n], 0, 0, 0);
        __builtin_amdgcn_s_setprio(0);
    }

    const int rg = (lane >> 4) * 4;
    #pragma unroll
    for (int m = 0; m < 4; ++m)
        #pragma unroll
        for (int n = 0; n < 4; ++n) {
            float* Cp = C + (size_t)(bm + wy * 64 + m * 16 + rg) * N + bn + wx * 64 + n * 16 + l15;
            #pragma unroll
            for (int r = 0; r < 4; ++r) Cp[(size_t)r * N] = acc[m][n][r];
        }
}

// ---------------------------------------------------------------------------
// RoPE on q (from fused qkv fp32) -> q_bf [h][s][d], pre-scaled by
// qscale * log2(e) so flash can use exp2 directly.
// ---------------------------------------------------------------------------
#define QSC (0.08838834764831845f * 1.4426950408889634f)

__global__ __launch_bounds__(256) void rope_q(const float* __restrict__ qkv,
                                              const float* __restrict__ freq,
                                              unsigned short* __restrict__ qbf)
{
    const int idx = blockIdx.x * 256 + threadIdx.x;  // NHQ*S*64
    const int d = idx & 63;
    const int s = (idx >> 6) & (S_LEN - 1);
    const int h = idx >> 17;
    const float f0 = freq[s * HD + d];
    const float f1 = freq[s * HD + d + 64];
    const float x0 = qkv[(size_t)s * NQKV + h * HD + d];
    const float x1 = qkv[(size_t)s * NQKV + h * HD + d + 64];
    const size_t ob = ((size_t)h * S_LEN + s) * HD + d;
    qbf[ob]      = f2bf((x0 * cosf(f0) - x1 * sinf(f0)) * QSC);
    qbf[ob + 64] = f2bf((x1 * cosf(f1) + x0 * sinf(f1)) * QSC);
}

// ---------------------------------------------------------------------------
// RoPE on k + transpose into d_out (fp32) and k_bf [h][s][d]; v copied.
// ---------------------------------------------------------------------------
__global__ __launch_bounds__(256) void rope_kv(const float* __restrict__ qkv,
                                               const float* __restrict__ freq,
                                               float* __restrict__ knew,
                                               float* __restrict__ vnew,
                                               unsigned short* __restrict__ kbf)
{
    const int idx = blockIdx.x * 256 + threadIdx.x;  // NHKV*S*64
    const int d = idx & 63;
    const int s = (idx >> 6) & (S_LEN - 1);
    const int h = idx >> 17;
    const float f0 = freq[s * HD + d];
    const float f1 = freq[s * HD + d + 64];
    const size_t ib = (size_t)s * NQKV + 4096 + h * HD + d;
    const float k0 = qkv[ib], k1 = qkv[ib + 64];
    const float v0 = qkv[ib + 1024], v1 = qkv[ib + 1024 + 64];
    const float k0r = k0 * cosf(f0) - k1 * sinf(f0);
    const float k1r = k1 * cosf(f1) + k0 * sinf(f1);
    const size_t ob = ((size_t)h * S_LEN + s) * HD + d;
    knew[ob] = k0r;       knew[ob + 64] = k1r;
    vnew[ob] = v0;        vnew[ob + 64] = v1;
    kbf[ob]  = f2bf(k0r); kbf[ob + 64]  = f2bf(k1r);
}

// ---------------------------------------------------------------------------
// V transpose: qkv fp32 v-part [s][d] -> vT bf16 [h][d][s]  (LDS-tiled)
// ---------------------------------------------------------------------------
__global__ __launch_bounds__(256) void transp_v(const float* __restrict__ qkv,
                                                unsigned short* __restrict__ vT)
{
    __shared__ unsigned short T[64][72];
    const int s0 = blockIdx.x * 64;
    const int dt = blockIdx.y & 1;
    const int h  = blockIdx.y >> 1;
    const int d0 = dt * 64;
    const int tid = threadIdx.x;
    #pragma unroll
    for (int c = 0; c < 4; ++c) {
        const int i = tid + c * 256;
        const int r  = i >> 4;
        const int cc = (i & 15) * 4;
        const float4 v = *(const float4*)(qkv + (size_t)(s0 + r) * NQKV + 5120 + h * HD + d0 + cc);
        T[r][cc + 0] = f2bf(v.x); T[r][cc + 1] = f2bf(v.y);
        T[r][cc + 2] = f2bf(v.z); T[r][cc + 3] = f2bf(v.w);
    }
    __syncthreads();
    #pragma unroll
    for (int c = 0; c < 2; ++c) {
        const int i = tid + c * 256;
        const int dr = i >> 3;
        const int sc = (i & 7) * 8;
        u16x8 o;
        #pragma unroll
        for (int j = 0; j < 8; ++j) o[j] = T[sc + j][dr];
        *(u16x8*)(vT + ((size_t)(h * HD + d0 + dr)) * S_LEN + s0 + sc) = o;
    }
}

// ---------------------------------------------------------------------------
// MFMA flash attention v2 (unchanged from round 3).
// ---------------------------------------------------------------------------
__global__ __launch_bounds__(256) void flash_bf16(const unsigned short* __restrict__ Qbf,
                                                  const unsigned short* __restrict__ Kbf,
                                                  const unsigned short* __restrict__ VbfT,
                                                  unsigned short* __restrict__ Obf)
{
    __shared__ __align__(16) unsigned short Ks[2][64 * 128];
    __shared__ __align__(16) unsigned short Vs[2][128 * 64];
    __shared__ __align__(16) unsigned short Ps[4][16 * 64];

    const int h  = blockIdx.x;
    const int yq = blockIdx.y;
    const int qt = (yq & 1) ? (31 - (yq >> 1)) : (yq >> 1);
    const int hkv = h >> 2;
    const int tid = threadIdx.x;
    const int lane = tid & 63;
    const int w = tid >> 6;
    const int l15 = lane & 15;
    const int l4  = lane >> 4;
    const int ldsWaveBase = (tid & 192) * 16;

    const char* Kg = (const char*)Kbf + (size_t)hkv * S_LEN * HD * 2;
    const char* Vg = (const char*)VbfT + (size_t)hkv * HD * S_LEN * 2;

    bf16x8 qf[4];
    {
        const char* Qg = (const char*)Qbf + ((size_t)h * S_LEN + qt * 64 + w * 16 + l15) * 256;
        #pragma unroll
        for (int kb = 0; kb < 4; ++kb)
            qf[kb] = *(const bf16x8*)(Qg + kb * 64 + l4 * 16);
    }

    auto STAGE = [&](int buf, int kt) {
        #pragma unroll
        for (int c = 0; c < 4; ++c) {
            const int i = tid + c * 256;
            const int kr = i >> 4;
            const int cc = (i & 15) ^ (kr & 7);
            gload16(Kg + (size_t)(kt * 64 + kr) * 256 + cc * 16,
                    (char*)Ks[buf] + ldsWaveBase + c * 4096);
        }
        #pragma unroll
        for (int c = 0; c < 4; ++c) {
            const int i = tid + c * 256;
            const int dr = i >> 3;
            const int cc = (i & 7) ^ (dr & 7);
            gload16(Vg + (size_t)dr * (S_LEN * 2) + (size_t)kt * 128 + cc * 16,
                    (char*)Vs[buf] + ldsWaveBase + c * 4096);
        }
    };

    f32x4 accO[8];
    #pragma unroll
    for (int n = 0; n < 8; ++n) accO[n] = (f32x4){0.f, 0.f, 0.f, 0.f};
    float m_i[4] = {-3e38f, -3e38f, -3e38f, -3e38f};
    float l_i[4] = {0.f, 0.f, 0.f, 0.f};

    STAGE(0, 0);
    __syncthreads();

    for (int kt = 0; kt <= qt; ++kt) {
        const int cbuf = kt & 1;
        if (kt < qt) STAGE(cbuf ^ 1, kt + 1);

        f32x4 sacc[4];
        #pragma unroll
        for (int n = 0; n < 4; ++n) sacc[n] = (f32x4){0.f, 0.f, 0.f, 0.f};
        __builtin_amdgcn_s_setprio(1);
        #pragma unroll
        for (int kb = 0; kb < 4; ++kb) {
            #pragma unroll
            for (int n = 0; n < 4; ++n) {
                const int krow = n * 16 + l15;
                const bf16x8 bk = *(const bf16x8*)((const char*)Ks[cbuf] + krow * 256 +
                                     ((kb * 64 + l4 * 16) ^ ((krow & 7) << 4)));
                sacc[n] = __builtin_amdgcn_mfma_f32_16x16x32_bf16(qf[kb], bk, sacc[n], 0, 0, 0);
            }
        }
        __builtin_amdgcn_s_setprio(0);

        float s0v[4], s1v[4], s2v[4], s3v[4], pm[4];
        #pragma unroll
        for (int reg = 0; reg < 4; ++reg) {
            float s0 = sacc[0][reg], s1 = sacc[1][reg];
            float s2 = sacc[2][reg], s3 = sacc[3][reg];
            if (kt == qt) {
                const int qglob = qt * 64 + w * 16 + l4 * 4 + reg;
                const int kvb = kt * 64 + l15;
                if (kvb +  0 > qglob) s0 = -3e38f;
                if (kvb + 16 > qglob) s1 = -3e38f;
                if (kvb + 32 > qglob) s2 = -3e38f;
                if (kvb + 48 > qglob) s3 = -3e38f;
            }
            float rmax = fmaxf(fmaxf(s0, s1), fmaxf(s2, s3));
            rmax = fmaxf(rmax, __shfl_xor(rmax, 1));
            rmax = fmaxf(rmax, __shfl_xor(rmax, 2));
            rmax = fmaxf(rmax, __shfl_xor(rmax, 4));
            rmax = fmaxf(rmax, __shfl_xor(rmax, 8));
            pm[reg] = rmax;
            s0v[reg] = s0; s1v[reg] = s1; s2v[reg] = s2; s3v[reg] = s3;
        }

        const bool grew = (pm[0] > m_i[0] + 8.f) || (pm[1] > m_i[1] + 8.f) ||
                          (pm[2] > m_i[2] + 8.f) || (pm[3] > m_i[3] + 8.f);
        if (__any(grew)) {
            #pragma unroll
            for (int reg = 0; reg < 4; ++reg) {
                const float mnew = fmaxf(m_i[reg], pm[reg]);
                const float csc = exp2f(m_i[reg] - mnew);
                l_i[reg] *= csc;
                m_i[reg] = mnew;
                #pragma unroll
                for (int n = 0; n < 8; ++n) accO[n][reg] *= csc;
            }
        }

        unsigned short* Pw = &Ps[w][0];
        #pragma unroll
        for (int reg = 0; reg < 4; ++reg) {
            const float p0 = exp2f(s0v[reg] - m_i[reg]);
            const float p1 = exp2f(s1v[reg] - m_i[reg]);
            const float p2 = exp2f(s2v[reg] - m_i[reg]);
            const float p3 = exp2f(s3v[reg] - m_i[reg]);
            const int rl = l4 * 4 + reg;
            const int sf = (rl & 7) << 4;
            *(unsigned short*)((char*)Pw + rl * 128 + (( 0 + l15 * 2) ^ sf)) = f2bf(p0);
            *(unsigned short*)((char*)Pw + rl * 128 + ((32 + l15 * 2) ^ sf)) = f2bf(p1);
            *(unsigned short*)((char*)Pw + rl * 128 + ((64 + l15 * 2) ^ sf)) = f2bf(p2);
            *(unsigned short*)((char*)Pw + rl * 128 + ((96 + l15 * 2) ^ sf)) = f2bf(p3);
            float rsum = p0 + p1 + p2 + p3;
            rsum += __shfl_xor(rsum, 1);
            rsum += __shfl_xor(rsum, 2);
            rsum += __shfl_xor(rsum, 4);
            rsum += __shfl_xor(rsum, 8);
            l_i[reg] += rsum;
        }

        const char* Pwb = (const char*)Pw;
        __builtin_amdgcn_s_setprio(1);
        #pragma unroll
        for (int kb = 0; kb < 2; ++kb) {
            const bf16x8 pa = *(const bf16x8*)(Pwb + l15 * 128 +
                                 ((kb * 64 + l4 * 16) ^ ((l15 & 7) << 4)));
            #pragma unroll
            for (int n = 0; n < 8; ++n) {
                const int vrow = n * 16 + l15;
                const bf16x8 vb = *(const bf16x8*)((const char*)Vs[cbuf] + vrow * 128 +
                                     ((kb * 64 + l4 * 16) ^ ((vrow & 7) << 4)));
                accO[n] = __builtin_amdgcn_mfma_f32_16x16x32_bf16(pa, vb, accO[n], 0, 0, 0);
            }
        }
        __builtin_amdgcn_s_setprio(0);

        __syncthreads();
    }

    float invl[4];
    #pragma unroll
    for (int reg = 0; reg < 4; ++reg) invl[reg] = 1.f / l_i[reg];
    #pragma unroll
    for (int n = 0; n < 8; ++n)
        #pragma unroll
        for (int reg = 0; reg < 4; ++reg) {
            const int row = qt * 64 + w * 16 + l4 * 4 + reg;
            Obf[(size_t)row * DQ + h * HD + n * 16 + l15] = f2bf(accO[n][reg] * invl[reg]);
        }
}

// ---------------------------------------------------------------------------
// d_out (fp32): [ out: S*DQ | k_new: NHKV*S*HD | v_new: NHKV*S*HD ]
// d_ws: x_bf 16MB @0 (attn_bf aliases) | wqkv_bf 48MB @16 (wo_bf aliases)
//       qkv_f32 48MB @64 | q_bf 16MB @112 | k_bf 4MB @128 | vT_bf 4MB @132
// ---------------------------------------------------------------------------
extern "C" void kernel_launch(void* const* d_in, const int* in_sizes, int n_in,
                              void* d_out, int out_size, void* d_ws, size_t ws_size,
                              hipStream_t stream)
{
    const float* x    = (const float*)d_in[0];
    const float* freq = (const float*)d_in[1];
    const float* wq   = (const float*)d_in[2];
    const float* wk   = (const float*)d_in[3];
    const float* wv   = (const float*)d_in[4];
    const float* wo   = (const float*)d_in[5];

    float* out  = (float*)d_out;
    float* knew = out + (size_t)S_LEN * DQ;
    float* vnew = knew + (size_t)NHKV * S_LEN * HD;

    char* ws = (char*)d_ws;
    unsigned short* x_bf    = (unsigned short*)(ws);
    unsigned short* attn_bf = (unsigned short*)(ws);               // aliases x_bf
    unsigned short* wqkv_bf = (unsigned short*)(ws + (16u << 20));
    unsigned short* wo_bf   = (unsigned short*)(ws + (16u << 20)); // aliases wqkv
    float*          qkv_f32 = (float*)(ws + (64u << 20));
    unsigned short* q_bf    = (unsigned short*)(ws + (112u << 20));
    unsigned short* k_bf    = (unsigned short*)(ws + (128u << 20));
    unsigned short* vT_bf   = (unsigned short*)(ws + (132u << 20));

    const dim3 blk(256);

    cvt_bf16<<<2048, blk, 0, stream>>>(x,  x_bf, S_LEN * DMODEL / 8);
    cvt_bf16<<<2048, blk, 0, stream>>>(wq, wqkv_bf, DQ * DMODEL / 8);
    cvt_bf16<<<1024, blk, 0, stream>>>(wk, wqkv_bf + (size_t)DQ * DMODEL, DKV * DMODEL / 8);
    cvt_bf16<<<1024, blk, 0, stream>>>(wv, wqkv_bf + (size_t)(DQ + DKV) * DMODEL, DKV * DMODEL / 8);

    // fused QKV projection: [2048,6144] = x @ [wq;wk;wv]^T
    gemm_bf16<<<dim3(NQKV / BBN, S_LEN / BBM), blk, 0, stream>>>(x_bf, wqkv_bf, qkv_f32, S_LEN, NQKV, DMODEL);

    cvt_bf16<<<2048, blk, 0, stream>>>(wo, wo_bf, DMODEL * DQ / 8);

    rope_q<<<NHQ * S_LEN * 64 / 256, blk, 0, stream>>>(qkv_f32, freq, q_bf);
    rope_kv<<<NHKV * S_LEN * 64 / 256, blk, 0, stream>>>(qkv_f32, freq, knew, vnew, k_bf);
    transp_v<<<dim3(S_LEN / 64, 2 * NHKV), blk, 0, stream>>>(qkv_f32, vT_bf);

    flash_bf16<<<dim3(NHQ, S_LEN / 64), blk, 0, stream>>>(q_bf, k_bf, vT_bf, attn_bf);

    // output projection: out = attn @ wo^T
    gemm_bf16<<<dim3(DMODEL / BBN, S_LEN / BBM), blk, 0, stream>>>(attn_bf, wo_bf, out, S_LEN, DMODEL, DMODEL);
}

// Round 7
// 602.662 us; speedup vs baseline: 1.0176x; 1.0176x over previous
//
#include <hip/hip_runtime.h>
#include <math.h>

#define S_LEN 2048
#define DMODEL 4096
#define NHQ 32
#define NHKV 8
#define HD 128
#define DQ 4096
#define DKV 1024
#define NQKV 6144   // 4096 q + 1024 k + 1024 v

typedef __attribute__((ext_vector_type(8))) short bf16x8;
typedef __attribute__((ext_vector_type(4))) float f32x4;
typedef __attribute__((ext_vector_type(8))) unsigned short u16x8;

__device__ __forceinline__ unsigned short f2bf(float f) {
    unsigned u = __builtin_bit_cast(unsigned, f);
    u += 0x7fffu + ((u >> 16) & 1u);     // round-to-nearest-even
    return (unsigned short)(u >> 16);
}

__device__ __forceinline__ void gload16(const void* g, void* l) {
    __builtin_amdgcn_global_load_lds(
        (const __attribute__((address_space(1))) unsigned int*)g,
        (__attribute__((address_space(3))) unsigned int*)l, 16, 0, 0);
}

// ---------------------------------------------------------------------------
// fp32 -> bf16 bulk convert (8 elems/thread/iter)
// ---------------------------------------------------------------------------
__global__ __launch_bounds__(256) void cvt_bf16(const float* __restrict__ src,
                                                unsigned short* __restrict__ dst, int n8)
{
    for (int i = blockIdx.x * 256 + threadIdx.x; i < n8; i += gridDim.x * 256) {
        const float4 a = ((const float4*)src)[2 * i];
        const float4 b = ((const float4*)src)[2 * i + 1];
        u16x8 o;
        o[0] = f2bf(a.x); o[1] = f2bf(a.y); o[2] = f2bf(a.z); o[3] = f2bf(a.w);
        o[4] = f2bf(b.x); o[5] = f2bf(b.y); o[6] = f2bf(b.z); o[7] = f2bf(b.w);
        ((u16x8*)dst)[i] = o;
    }
}

// ---------------------------------------------------------------------------
// bf16 MFMA GEMM, ring-4 counted-vmcnt pipeline (T3/T4 on the m97 skeleton).
// C[M,N] = A[M,K]*B[N,K]^T fp32. 128x128 tile, BK=32, 4 waves, 4x4 frags.
// 4 LDS slots (64KB, 2 blocks/CU); iteration t stages tile t+3 and waits
// vmcnt(12) so 3 tiles of global_load_lds stay in flight ACROSS barriers
// (raw s_barrier, no vmcnt(0) drain — the m97 structural stall).
// NO XCD swizzle: round-5 A/B showed the default round-robin mapping gives
// each XCD a 6-of-48 B-column slice (disjoint L2 partitioning, FETCH=108MB);
// the "contiguous chunk" swizzle spread all columns to every XCD (341MB).
// ---------------------------------------------------------------------------
#define BBM 128
#define BBN 128
#define BBK 32

__global__ __launch_bounds__(256) void gemm_bf16(const unsigned short* __restrict__ A,
                                                 const unsigned short* __restrict__ B,
                                                 float* __restrict__ C,
                                                 int M, int N, int K)
{
    __shared__ __align__(16) unsigned short As[4][BBM * BBK];  // 4 x 8KB
    __shared__ __align__(16) unsigned short Bs[4][BBN * BBK];  // 4 x 8KB

    const int tid  = threadIdx.x;
    const int lane = tid & 63;
    const int w    = tid >> 6;
    const int wy   = w >> 1, wx = w & 1;
    const int bm = blockIdx.y * BBM, bn = blockIdx.x * BBN;

    const int l15 = lane & 15;
    const int lk16 = (lane >> 4) * 16;
    const int ldsWaveBase = (tid & 192) * 16;

    f32x4 acc[4][4];
    #pragma unroll
    for (int m = 0; m < 4; ++m)
        #pragma unroll
        for (int n = 0; n < 4; ++n) acc[m][n] = (f32x4){0.f, 0.f, 0.f, 0.f};

    const char* Ab = (const char*)A;
    const char* Bb = (const char*)B;
    const int NT = K / BBK;   // 128 for K=4096

    auto STAGE = [&](int slot, int t) {
        #pragma unroll
        for (int c = 0; c < 2; ++c) {
            const int i = tid + c * 256;
            const int r = i >> 2;
            const int co = (i & 3) << 4;
            gload16(Ab + ((size_t)(bm + r) * K + t * BBK) * 2 + co,
                    (char*)As + slot * 8192 + ldsWaveBase + c * 4096);
            gload16(Bb + ((size_t)(bn + r) * K + t * BBK) * 2 + co,
                    (char*)Bs + slot * 8192 + ldsWaveBase + c * 4096);
        }
    };

    STAGE(0, 0); STAGE(1, 1); STAGE(2, 2);   // 12 loads/thread in flight

    for (int t = 0; t < NT; ++t) {
        // B1: all waves done READING slot (t+3)&3 (== (t-1)&3, read last iter).
        __builtin_amdgcn_sched_barrier(0);
        asm volatile("s_waitcnt lgkmcnt(0)" ::: "memory");
        __builtin_amdgcn_s_barrier();        // raw: no vmcnt drain
        __builtin_amdgcn_sched_barrier(0);

        const int ts = t + 3;
        if (ts < NT) STAGE(ts & 3, ts);

        // counted wait: tile t's 4 loads complete; up to 12 newer stay in flight
        const int rem = NT - 1 - t;
        if (rem >= 3)      asm volatile("s_waitcnt vmcnt(12)" ::: "memory");
        else if (rem == 2) asm volatile("s_waitcnt vmcnt(8)"  ::: "memory");
        else if (rem == 1) asm volatile("s_waitcnt vmcnt(4)"  ::: "memory");
        else               asm volatile("s_waitcnt vmcnt(0)"  ::: "memory");
        __builtin_amdgcn_sched_barrier(0);
        __builtin_amdgcn_s_barrier();        // B2: tile t visible block-wide
        __builtin_amdgcn_sched_barrier(0);

        const char* Asl = (const char*)As + (t & 3) * 8192;
        const char* Bsl = (const char*)Bs + (t & 3) * 8192;
        bf16x8 af[4], bfr[4];
        #pragma unroll
        for (int m = 0; m < 4; ++m)
            af[m] = *(const bf16x8*)(Asl + (wy * 64 + m * 16 + l15) * 64 + lk16);
        #pragma unroll
        for (int n = 0; n < 4; ++n)
            bfr[n] = *(const bf16x8*)(Bsl + (wx * 64 + n * 16 + l15) * 64 + lk16);
        __builtin_amdgcn_s_setprio(1);
        #pragma unroll
        for (int m = 0; m < 4; ++m)
            #pragma unroll
            for (int n = 0; n < 4; ++n)
                acc[m][n] = __builtin_amdgcn_mfma_f32_16x16x32_bf16(af[m], bfr[n], acc[m][n], 0, 0, 0);
        __builtin_amdgcn_s_setprio(0);
    }

    const int rg = (lane >> 4) * 4;
    #pragma unroll
    for (int m = 0; m < 4; ++m)
        #pragma unroll
        for (int n = 0; n < 4; ++n) {
            float* Cp = C + (size_t)(bm + wy * 64 + m * 16 + rg) * N + bn + wx * 64 + n * 16 + l15;
            #pragma unroll
            for (int r = 0; r < 4; ++r) Cp[(size_t)r * N] = acc[m][n][r];
        }
}

// ---------------------------------------------------------------------------
// RoPE on q (from fused qkv fp32) -> q_bf [h][s][d], pre-scaled by
// qscale * log2(e) so flash can use exp2 directly.
// ---------------------------------------------------------------------------
#define QSC (0.08838834764831845f * 1.4426950408889634f)

__global__ __launch_bounds__(256) void rope_q(const float* __restrict__ qkv,
                                              const float* __restrict__ freq,
                                              unsigned short* __restrict__ qbf)
{
    const int idx = blockIdx.x * 256 + threadIdx.x;  // NHQ*S*64
    const int d = idx & 63;
    const int s = (idx >> 6) & (S_LEN - 1);
    const int h = idx >> 17;
    const float f0 = freq[s * HD + d];
    const float f1 = freq[s * HD + d + 64];
    const float x0 = qkv[(size_t)s * NQKV + h * HD + d];
    const float x1 = qkv[(size_t)s * NQKV + h * HD + d + 64];
    const size_t ob = ((size_t)h * S_LEN + s) * HD + d;
    qbf[ob]      = f2bf((x0 * cosf(f0) - x1 * sinf(f0)) * QSC);
    qbf[ob + 64] = f2bf((x1 * cosf(f1) + x0 * sinf(f1)) * QSC);
}

// ---------------------------------------------------------------------------
// RoPE on k + transpose into d_out (fp32) and k_bf [h][s][d]; v copied.
// ---------------------------------------------------------------------------
__global__ __launch_bounds__(256) void rope_kv(const float* __restrict__ qkv,
                                               const float* __restrict__ freq,
                                               float* __restrict__ knew,
                                               float* __restrict__ vnew,
                                               unsigned short* __restrict__ kbf)
{
    const int idx = blockIdx.x * 256 + threadIdx.x;  // NHKV*S*64
    const int d = idx & 63;
    const int s = (idx >> 6) & (S_LEN - 1);
    const int h = idx >> 17;
    const float f0 = freq[s * HD + d];
    const float f1 = freq[s * HD + d + 64];
    const size_t ib = (size_t)s * NQKV + 4096 + h * HD + d;
    const float k0 = qkv[ib], k1 = qkv[ib + 64];
    const float v0 = qkv[ib + 1024], v1 = qkv[ib + 1024 + 64];
    const float k0r = k0 * cosf(f0) - k1 * sinf(f0);
    const float k1r = k1 * cosf(f1) + k0 * sinf(f1);
    const size_t ob = ((size_t)h * S_LEN + s) * HD + d;
    knew[ob] = k0r;       knew[ob + 64] = k1r;
    vnew[ob] = v0;        vnew[ob + 64] = v1;
    kbf[ob]  = f2bf(k0r); kbf[ob + 64]  = f2bf(k1r);
}

// ---------------------------------------------------------------------------
// V transpose: qkv fp32 v-part [s][d] -> vT bf16 [h][d][s]  (LDS-tiled)
// ---------------------------------------------------------------------------
__global__ __launch_bounds__(256) void transp_v(const float* __restrict__ qkv,
                                                unsigned short* __restrict__ vT)
{
    __shared__ unsigned short T[64][72];
    const int s0 = blockIdx.x * 64;
    const int dt = blockIdx.y & 1;
    const int h  = blockIdx.y >> 1;
    const int d0 = dt * 64;
    const int tid = threadIdx.x;
    #pragma unroll
    for (int c = 0; c < 4; ++c) {
        const int i = tid + c * 256;
        const int r  = i >> 4;
        const int cc = (i & 15) * 4;
        const float4 v = *(const float4*)(qkv + (size_t)(s0 + r) * NQKV + 5120 + h * HD + d0 + cc);
        T[r][cc + 0] = f2bf(v.x); T[r][cc + 1] = f2bf(v.y);
        T[r][cc + 2] = f2bf(v.z); T[r][cc + 3] = f2bf(v.w);
    }
    __syncthreads();
    #pragma unroll
    for (int c = 0; c < 2; ++c) {
        const int i = tid + c * 256;
        const int dr = i >> 3;
        const int sc = (i & 7) * 8;
        u16x8 o;
        #pragma unroll
        for (int j = 0; j < 8; ++j) o[j] = T[sc + j][dr];
        *(u16x8*)(vT + ((size_t)(h * HD + d0 + dr)) * S_LEN + s0 + sc) = o;
    }
}

// ---------------------------------------------------------------------------
// MFMA flash attention v2 (unchanged).
// ---------------------------------------------------------------------------
__global__ __launch_bounds__(256) void flash_bf16(const unsigned short* __restrict__ Qbf,
                                                  const unsigned short* __restrict__ Kbf,
                                                  const unsigned short* __restrict__ VbfT,
                                                  unsigned short* __restrict__ Obf)
{
    __shared__ __align__(16) unsigned short Ks[2][64 * 128];
    __shared__ __align__(16) unsigned short Vs[2][128 * 64];
    __shared__ __align__(16) unsigned short Ps[4][16 * 64];

    const int h  = blockIdx.x;
    const int yq = blockIdx.y;
    const int qt = (yq & 1) ? (31 - (yq >> 1)) : (yq >> 1);
    const int hkv = h >> 2;
    const int tid = threadIdx.x;
    const int lane = tid & 63;
    const int w = tid >> 6;
    const int l15 = lane & 15;
    const int l4  = lane >> 4;
    const int ldsWaveBase = (tid & 192) * 16;

    const char* Kg = (const char*)Kbf + (size_t)hkv * S_LEN * HD * 2;
    const char* Vg = (const char*)VbfT + (size_t)hkv * HD * S_LEN * 2;

    bf16x8 qf[4];
    {
        const char* Qg = (const char*)Qbf + ((size_t)h * S_LEN + qt * 64 + w * 16 + l15) * 256;
        #pragma unroll
        for (int kb = 0; kb < 4; ++kb)
            qf[kb] = *(const bf16x8*)(Qg + kb * 64 + l4 * 16);
    }

    auto STAGE = [&](int buf, int kt) {
        #pragma unroll
        for (int c = 0; c < 4; ++c) {
            const int i = tid + c * 256;
            const int kr = i >> 4;
            const int cc = (i & 15) ^ (kr & 7);
            gload16(Kg + (size_t)(kt * 64 + kr) * 256 + cc * 16,
                    (char*)Ks[buf] + ldsWaveBase + c * 4096);
        }
        #pragma unroll
        for (int c = 0; c < 4; ++c) {
            const int i = tid + c * 256;
            const int dr = i >> 3;
            const int cc = (i & 7) ^ (dr & 7);
            gload16(Vg + (size_t)dr * (S_LEN * 2) + (size_t)kt * 128 + cc * 16,
                    (char*)Vs[buf] + ldsWaveBase + c * 4096);
        }
    };

    f32x4 accO[8];
    #pragma unroll
    for (int n = 0; n < 8; ++n) accO[n] = (f32x4){0.f, 0.f, 0.f, 0.f};
    float m_i[4] = {-3e38f, -3e38f, -3e38f, -3e38f};
    float l_i[4] = {0.f, 0.f, 0.f, 0.f};

    STAGE(0, 0);
    __syncthreads();

    for (int kt = 0; kt <= qt; ++kt) {
        const int cbuf = kt & 1;
        if (kt < qt) STAGE(cbuf ^ 1, kt + 1);

        f32x4 sacc[4];
        #pragma unroll
        for (int n = 0; n < 4; ++n) sacc[n] = (f32x4){0.f, 0.f, 0.f, 0.f};
        __builtin_amdgcn_s_setprio(1);
        #pragma unroll
        for (int kb = 0; kb < 4; ++kb) {
            #pragma unroll
            for (int n = 0; n < 4; ++n) {
                const int krow = n * 16 + l15;
                const bf16x8 bk = *(const bf16x8*)((const char*)Ks[cbuf] + krow * 256 +
                                     ((kb * 64 + l4 * 16) ^ ((krow & 7) << 4)));
                sacc[n] = __builtin_amdgcn_mfma_f32_16x16x32_bf16(qf[kb], bk, sacc[n], 0, 0, 0);
            }
        }
        __builtin_amdgcn_s_setprio(0);

        float s0v[4], s1v[4], s2v[4], s3v[4], pm[4];
        #pragma unroll
        for (int reg = 0; reg < 4; ++reg) {
            float s0 = sacc[0][reg], s1 = sacc[1][reg];
            float s2 = sacc[2][reg], s3 = sacc[3][reg];
            if (kt == qt) {
                const int qglob = qt * 64 + w * 16 + l4 * 4 + reg;
                const int kvb = kt * 64 + l15;
                if (kvb +  0 > qglob) s0 = -3e38f;
                if (kvb + 16 > qglob) s1 = -3e38f;
                if (kvb + 32 > qglob) s2 = -3e38f;
                if (kvb + 48 > qglob) s3 = -3e38f;
            }
            float rmax = fmaxf(fmaxf(s0, s1), fmaxf(s2, s3));
            rmax = fmaxf(rmax, __shfl_xor(rmax, 1));
            rmax = fmaxf(rmax, __shfl_xor(rmax, 2));
            rmax = fmaxf(rmax, __shfl_xor(rmax, 4));
            rmax = fmaxf(rmax, __shfl_xor(rmax, 8));
            pm[reg] = rmax;
            s0v[reg] = s0; s1v[reg] = s1; s2v[reg] = s2; s3v[reg] = s3;
        }

        const bool grew = (pm[0] > m_i[0] + 8.f) || (pm[1] > m_i[1] + 8.f) ||
                          (pm[2] > m_i[2] + 8.f) || (pm[3] > m_i[3] + 8.f);
        if (__any(grew)) {
            #pragma unroll
            for (int reg = 0; reg < 4; ++reg) {
                const float mnew = fmaxf(m_i[reg], pm[reg]);
                const float csc = exp2f(m_i[reg] - mnew);
                l_i[reg] *= csc;
                m_i[reg] = mnew;
                #pragma unroll
                for (int n = 0; n < 8; ++n) accO[n][reg] *= csc;
            }
        }

        unsigned short* Pw = &Ps[w][0];
        #pragma unroll
        for (int reg = 0; reg < 4; ++reg) {
            const float p0 = exp2f(s0v[reg] - m_i[reg]);
            const float p1 = exp2f(s1v[reg] - m_i[reg]);
            const float p2 = exp2f(s2v[reg] - m_i[reg]);
            const float p3 = exp2f(s3v[reg] - m_i[reg]);
            const int rl = l4 * 4 + reg;
            const int sf = (rl & 7) << 4;
            *(unsigned short*)((char*)Pw + rl * 128 + (( 0 + l15 * 2) ^ sf)) = f2bf(p0);
            *(unsigned short*)((char*)Pw + rl * 128 + ((32 + l15 * 2) ^ sf)) = f2bf(p1);
            *(unsigned short*)((char*)Pw + rl * 128 + ((64 + l15 * 2) ^ sf)) = f2bf(p2);
            *(unsigned short*)((char*)Pw + rl * 128 + ((96 + l15 * 2) ^ sf)) = f2bf(p3);
            float rsum = p0 + p1 + p2 + p3;
            rsum += __shfl_xor(rsum, 1);
            rsum += __shfl_xor(rsum, 2);
            rsum += __shfl_xor(rsum, 4);
            rsum += __shfl_xor(rsum, 8);
            l_i[reg] += rsum;
        }

        const char* Pwb = (const char*)Pw;
        __builtin_amdgcn_s_setprio(1);
        #pragma unroll
        for (int kb = 0; kb < 2; ++kb) {
            const bf16x8 pa = *(const bf16x8*)(Pwb + l15 * 128 +
                                 ((kb * 64 + l4 * 16) ^ ((l15 & 7) << 4)));
            #pragma unroll
            for (int n = 0; n < 8; ++n) {
                const int vrow = n * 16 + l15;
                const bf16x8 vb = *(const bf16x8*)((const char*)Vs[cbuf] + vrow * 128 +
                                     ((kb * 64 + l4 * 16) ^ ((vrow & 7) << 4)));
                accO[n] = __builtin_amdgcn_mfma_f32_16x16x32_bf16(pa, vb, accO[n], 0, 0, 0);
            }
        }
        __builtin_amdgcn_s_setprio(0);

        __syncthreads();
    }

    float invl[4];
    #pragma unroll
    for (int reg = 0; reg < 4; ++reg) invl[reg] = 1.f / l_i[reg];
    #pragma unroll
    for (int n = 0; n < 8; ++n)
        #pragma unroll
        for (int reg = 0; reg < 4; ++reg) {
            const int row = qt * 64 + w * 16 + l4 * 4 + reg;
            Obf[(size_t)row * DQ + h * HD + n * 16 + l15] = f2bf(accO[n][reg] * invl[reg]);
        }
}

// ---------------------------------------------------------------------------
// d_out (fp32): [ out: S*DQ | k_new: NHKV*S*HD | v_new: NHKV*S*HD ]
// d_ws: x_bf 16MB @0 (attn_bf aliases) | wqkv_bf 48MB @16 (wo_bf aliases)
//       qkv_f32 48MB @64 | q_bf 16MB @112 | k_bf 4MB @128 | vT_bf 4MB @132
// ---------------------------------------------------------------------------
extern "C" void kernel_launch(void* const* d_in, const int* in_sizes, int n_in,
                              void* d_out, int out_size, void* d_ws, size_t ws_size,
                              hipStream_t stream)
{
    const float* x    = (const float*)d_in[0];
    const float* freq = (const float*)d_in[1];
    const float* wq   = (const float*)d_in[2];
    const float* wk   = (const float*)d_in[3];
    const float* wv   = (const float*)d_in[4];
    const float* wo   = (const float*)d_in[5];

    float* out  = (float*)d_out;
    float* knew = out + (size_t)S_LEN * DQ;
    float* vnew = knew + (size_t)NHKV * S_LEN * HD;

    char* ws = (char*)d_ws;
    unsigned short* x_bf    = (unsigned short*)(ws);
    unsigned short* attn_bf = (unsigned short*)(ws);               // aliases x_bf
    unsigned short* wqkv_bf = (unsigned short*)(ws + (16u << 20));
    unsigned short* wo_bf   = (unsigned short*)(ws + (16u << 20)); // aliases wqkv
    float*          qkv_f32 = (float*)(ws + (64u << 20));
    unsigned short* q_bf    = (unsigned short*)(ws + (112u << 20));
    unsigned short* k_bf    = (unsigned short*)(ws + (128u << 20));
    unsigned short* vT_bf   = (unsigned short*)(ws + (132u << 20));

    const dim3 blk(256);

    cvt_bf16<<<2048, blk, 0, stream>>>(x,  x_bf, S_LEN * DMODEL / 8);
    cvt_bf16<<<2048, blk, 0, stream>>>(wq, wqkv_bf, DQ * DMODEL / 8);
    cvt_bf16<<<1024, blk, 0, stream>>>(wk, wqkv_bf + (size_t)DQ * DMODEL, DKV * DMODEL / 8);
    cvt_bf16<<<1024, blk, 0, stream>>>(wv, wqkv_bf + (size_t)(DQ + DKV) * DMODEL, DKV * DMODEL / 8);

    // fused QKV projection: [2048,6144] = x @ [wq;wk;wv]^T
    gemm_bf16<<<dim3(NQKV / BBN, S_LEN / BBM), blk, 0, stream>>>(x_bf, wqkv_bf, qkv_f32, S_LEN, NQKV, DMODEL);

    cvt_bf16<<<2048, blk, 0, stream>>>(wo, wo_bf, DMODEL * DQ / 8);

    rope_q<<<NHQ * S_LEN * 64 / 256, blk, 0, stream>>>(qkv_f32, freq, q_bf);
    rope_kv<<<NHKV * S_LEN * 64 / 256, blk, 0, stream>>>(qkv_f32, freq, knew, vnew, k_bf);
    transp_v<<<dim3(S_LEN / 64, 2 * NHKV), blk, 0, stream>>>(qkv_f32, vT_bf);

    flash_bf16<<<dim3(NHQ, S_LEN / 64), blk, 0, stream>>>(q_bf, k_bf, vT_bf, attn_bf);

    // output projection: out = attn @ wo^T
    gemm_bf16<<<dim3(DMODEL / BBN, S_LEN / BBM), blk, 0, stream>>>(attn_bf, wo_bf, out, S_LEN, DMODEL, DMODEL);
}

// Round 10
// 589.514 us; speedup vs baseline: 1.0403x; 1.0223x over previous
//
#include <hip/hip_runtime.h>
#include <math.h>

#define S_LEN 2048
#define DMODEL 4096
#define NHQ 32
#define NHKV 8
#define HD 128
#define DQ 4096
#define DKV 1024
#define NQKV 6144   // 4096 q + 1024 k + 1024 v

typedef __attribute__((ext_vector_type(8))) short bf16x8;
typedef __attribute__((ext_vector_type(4))) float f32x4;
typedef __attribute__((ext_vector_type(8))) unsigned short u16x8;

__device__ __forceinline__ unsigned short f2bf(float f) {
    unsigned u = __builtin_bit_cast(unsigned, f);
    u += 0x7fffu + ((u >> 16) & 1u);     // round-to-nearest-even
    return (unsigned short)(u >> 16);
}

__device__ __forceinline__ void gload16(const void* g, void* l) {
    __builtin_amdgcn_global_load_lds(
        (const __attribute__((address_space(1))) unsigned int*)g,
        (__attribute__((address_space(3))) unsigned int*)l, 16, 0, 0);
}

// ---------------------------------------------------------------------------
// fp32 -> bf16 bulk convert
// ---------------------------------------------------------------------------
__global__ __launch_bounds__(256) void cvt_bf16(const float* __restrict__ src,
                                                unsigned short* __restrict__ dst, int n8)
{
    for (int i = blockIdx.x * 256 + threadIdx.x; i < n8; i += gridDim.x * 256) {
        const float4 a = ((const float4*)src)[2 * i];
        const float4 b = ((const float4*)src)[2 * i + 1];
        u16x8 o;
        o[0] = f2bf(a.x); o[1] = f2bf(a.y); o[2] = f2bf(a.z); o[3] = f2bf(a.w);
        o[4] = f2bf(b.x); o[5] = f2bf(b.y); o[6] = f2bf(b.z); o[7] = f2bf(b.w);
        ((u16x8*)dst)[i] = o;
    }
}

// ---------------------------------------------------------------------------
// 256x256 8-phase bf16 MFMA GEMM (T2+T3+T4+T5), C = A[M,K]*B[N,K]^T fp32.
// 512 thr, 8 waves (2M x 4N), per-wave C = 128x64, BK=64, dbuf LDS 128KB.
// Per K-tile: 4 phases; phase p stages ONE slice-pair of tile t+1 (order:
// A-mh0, B-nh0, B-nh1, A-mh1 = first-consumption order), waits vmcnt(6)
// (3 slice-pairs in flight, NEVER drains in main loop), one s_barrier,
// then 16 MFMAs (quadrant mh=p>>1, nh=p&1). st_16x32 swizzle applied as
// pre-swizzled global source (col ^= lane&32) + swizzled ds_read
// (addr ^= (l15&4)<<3) — same involution both sides (rule 21).
// ---------------------------------------------------------------------------
#define GBM 256
#define GBN 256

__global__ __launch_bounds__(512, 2) void gemm_bf16_256(const unsigned short* __restrict__ A,
                                                        const unsigned short* __restrict__ B,
                                                        float* __restrict__ C,
                                                        int M, int N, int K)
{
    __shared__ __align__(16) unsigned short As[2][256 * 64];  // 2 x 32KB
    __shared__ __align__(16) unsigned short Bs[2][256 * 64];  // 2 x 32KB

    const int tid  = threadIdx.x;
    const int lane = tid & 63;
    const int w    = tid >> 6;          // 0..7
    const int wy   = w >> 2, wx = w & 3;
    const int bm = blockIdx.y * GBM, bn = blockIdx.x * GBN;
    const int l15 = lane & 15, l4 = lane >> 4;
    const int lr  = lane >> 3;                           // staging: row offset 0..7
    const int lc  = ((lane & 7) * 16) ^ (lane & 32);     // staging: swizzled col byte
    const int swzR = (l15 & 4) << 3;                     // read-side flip (0 or 32)

    f32x4 acc[8][4];
    #pragma unroll
    for (int m = 0; m < 8; ++m)
        #pragma unroll
        for (int n = 0; n < 4; ++n) acc[m][n] = (f32x4){0.f, 0.f, 0.f, 0.f};

    const char* Ab = (const char*)A;
    const char* Bb = (const char*)B;
    const int NT = K / 64;

    // stage slice sl of K-tile kt into buf nb (2 gloads/thread = 16KB)
    // sl: 0 = A rows (mh0), 1 = B rows nh0, 2 = B nh1, 3 = A mh1
    auto STAGE = [&](int nb, int kt, int sl) {
        #pragma unroll
        for (int j = 0; j < 2; ++j) {
            const int rsb = w * 8 + j * 64;
            if (sl == 0 || sl == 3) {
                const int mh = (sl == 3);
                const int rb = (rsb & 63) + mh * 64 + ((rsb & 64) ? 128 : 0);
                gload16(Ab + ((size_t)(bm + rb + lr) * K + kt * 64) * 2 + lc,
                        (char*)As + nb * 32768 + rb * 128);
            } else {
                const int nh = (sl == 2);
                const int rb = (rsb >> 5) * 64 + nh * 32 + (rsb & 31);
                gload16(Bb + ((size_t)(bn + rb + lr) * K + kt * 64) * 2 + lc,
                        (char*)Bs + nb * 32768 + rb * 128);
            }
        }
    };

    // prologue: tile 0 into buf 0, in consumption order
    STAGE(0, 0, 0); STAGE(0, 0, 1); STAGE(0, 0, 2); STAGE(0, 0, 3);

    bf16x8 af[4][2], bfr[2][2];

    for (int t = 0; t < NT; ++t) {
        const int cb = t & 1, nb = cb ^ 1;
        const char* Ac = (const char*)As + cb * 32768;
        const char* Bc = (const char*)Bs + cb * 32768;
        const bool last = (t == NT - 1);

        #pragma unroll
        for (int p = 0; p < 4; ++p) {
            const int mh = p >> 1, nh = p & 1;

            if (!last) {
                STAGE(nb, t + 1, p);
                asm volatile("s_waitcnt vmcnt(6)" ::: "memory");
            } else {
                if (p == 0)      asm volatile("s_waitcnt vmcnt(4)" ::: "memory");
                else if (p == 1) asm volatile("s_waitcnt vmcnt(2)" ::: "memory");
                else             asm volatile("s_waitcnt vmcnt(0)" ::: "memory");
            }
            __builtin_amdgcn_sched_barrier(0);
            __builtin_amdgcn_s_barrier();
            __builtin_amdgcn_sched_barrier(0);

            if (nh == 0) {    // (re)load A frags for this mh (reused by nh=1 phase)
                #pragma unroll
                for (int mm = 0; mm < 4; ++mm)
                    #pragma unroll
                    for (int ks = 0; ks < 2; ++ks)
                        af[mm][ks] = *(const bf16x8*)(Ac +
                            (wy * 128 + (mh * 4 + mm) * 16 + l15) * 128 +
                            ((ks * 64 + l4 * 16) ^ swzR));
            }
            #pragma unroll
            for (int nn = 0; nn < 2; ++nn)
                #pragma unroll
                for (int ks = 0; ks < 2; ++ks)
                    bfr[nn][ks] = *(const bf16x8*)(Bc +
                        (wx * 64 + (nh * 2 + nn) * 16 + l15) * 128 +
                        ((ks * 64 + l4 * 16) ^ swzR));

            __builtin_amdgcn_s_setprio(1);
            #pragma unroll
            for (int ks = 0; ks < 2; ++ks)
                #pragma unroll
                for (int mm = 0; mm < 4; ++mm)
                    #pragma unroll
                    for (int nn = 0; nn < 2; ++nn)
                        acc[mh * 4 + mm][nh * 2 + nn] =
                            __builtin_amdgcn_mfma_f32_16x16x32_bf16(
                                af[mm][ks], bfr[nn][ks], acc[mh * 4 + mm][nh * 2 + nn], 0, 0, 0);
            __builtin_amdgcn_s_setprio(0);
        }
    }

    const int rg = l4 * 4;
    #pragma unroll
    for (int m = 0; m < 8; ++m)
        #pragma unroll
        for (int n = 0; n < 4; ++n) {
            float* Cp = C + (size_t)(bm + wy * 128 + m * 16 + rg) * N + bn + wx * 64 + n * 16 + l15;
            #pragma unroll
            for (int r = 0; r < 4; ++r) Cp[(size_t)r * N] = acc[m][n][r];
        }
}

// ---------------------------------------------------------------------------
// 128x128 2-barrier bf16 GEMM (round-3 proven, 157us O-proj) — control.
// ---------------------------------------------------------------------------
#define BBM 128
#define BBN 128
#define BBK 32

__global__ __launch_bounds__(256) void gemm_bf16(const unsigned short* __restrict__ A,
                                                 const unsigned short* __restrict__ B,
                                                 float* __restrict__ C,
                                                 int M, int N, int K)
{
    __shared__ __align__(16) unsigned short As[BBM * BBK];
    __shared__ __align__(16) unsigned short Bs[BBN * BBK];

    const int tid  = threadIdx.x;
    const int lane = tid & 63;
    const int w    = tid >> 6;
    const int wy   = w >> 1, wx = w & 1;
    const int bm = blockIdx.y * BBM, bn = blockIdx.x * BBN;
    const int l15 = lane & 15;
    const int lk16 = (lane >> 4) * 16;
    const int ldsWaveBase = (tid & 192) * 16;

    f32x4 acc[4][4];
    #pragma unroll
    for (int m = 0; m < 4; ++m)
        #pragma unroll
        for (int n = 0; n < 4; ++n) acc[m][n] = (f32x4){0.f, 0.f, 0.f, 0.f};

    const char* Ab = (const char*)A;
    const char* Bb = (const char*)B;
    char* AsB = (char*)As;
    char* BsB = (char*)Bs;

    for (int k0 = 0; k0 < K; k0 += BBK) {
        __syncthreads();
        #pragma unroll
        for (int c = 0; c < 2; ++c) {
            const int i = tid + c * 256;
            const int r = i >> 2;
            const int co = (i & 3) << 4;
            gload16(Ab + ((size_t)(bm + r) * K + k0) * 2 + co, AsB + ldsWaveBase + c * 4096);
            gload16(Bb + ((size_t)(bn + r) * K + k0) * 2 + co, BsB + ldsWaveBase + c * 4096);
        }
        __syncthreads();

        bf16x8 af[4], bfr[4];
        #pragma unroll
        for (int m = 0; m < 4; ++m)
            af[m] = *(const bf16x8*)(AsB + (wy * 64 + m * 16 + l15) * 64 + lk16);
        #pragma unroll
        for (int n = 0; n < 4; ++n)
            bfr[n] = *(const bf16x8*)(BsB + (wx * 64 + n * 16 + l15) * 64 + lk16);
        #pragma unroll
        for (int m = 0; m < 4; ++m)
            #pragma unroll
            for (int n = 0; n < 4; ++n)
                acc[m][n] = __builtin_amdgcn_mfma_f32_16x16x32_bf16(af[m], bfr[n], acc[m][n], 0, 0, 0);
    }

    const int rg = (lane >> 4) * 4;
    #pragma unroll
    for (int m = 0; m < 4; ++m)
        #pragma unroll
        for (int n = 0; n < 4; ++n) {
            float* Cp = C + (size_t)(bm + wy * 64 + m * 16 + rg) * N + bn + wx * 64 + n * 16 + l15;
            #pragma unroll
            for (int r = 0; r < 4; ++r) Cp[(size_t)r * N] = acc[m][n][r];
        }
}

// ---------------------------------------------------------------------------
// RoPE on q -> q_bf [h][s][d], pre-scaled by qscale*log2(e).
// ---------------------------------------------------------------------------
#define QSC (0.08838834764831845f * 1.4426950408889634f)

__global__ __launch_bounds__(256) void rope_q(const float* __restrict__ qkv,
                                              const float* __restrict__ freq,
                                              unsigned short* __restrict__ qbf)
{
    const int idx = blockIdx.x * 256 + threadIdx.x;
    const int d = idx & 63;
    const int s = (idx >> 6) & (S_LEN - 1);
    const int h = idx >> 17;
    const float f0 = freq[s * HD + d];
    const float f1 = freq[s * HD + d + 64];
    const float x0 = qkv[(size_t)s * NQKV + h * HD + d];
    const float x1 = qkv[(size_t)s * NQKV + h * HD + d + 64];
    const size_t ob = ((size_t)h * S_LEN + s) * HD + d;
    qbf[ob]      = f2bf((x0 * cosf(f0) - x1 * sinf(f0)) * QSC);
    qbf[ob + 64] = f2bf((x1 * cosf(f1) + x0 * sinf(f1)) * QSC);
}

__global__ __launch_bounds__(256) void rope_kv(const float* __restrict__ qkv,
                                               const float* __restrict__ freq,
                                               float* __restrict__ knew,
                                               float* __restrict__ vnew,
                                               unsigned short* __restrict__ kbf)
{
    const int idx = blockIdx.x * 256 + threadIdx.x;
    const int d = idx & 63;
    const int s = (idx >> 6) & (S_LEN - 1);
    const int h = idx >> 17;
    const float f0 = freq[s * HD + d];
    const float f1 = freq[s * HD + d + 64];
    const size_t ib = (size_t)s * NQKV + 4096 + h * HD + d;
    const float k0 = qkv[ib], k1 = qkv[ib + 64];
    const float v0 = qkv[ib + 1024], v1 = qkv[ib + 1024 + 64];
    const float k0r = k0 * cosf(f0) - k1 * sinf(f0);
    const float k1r = k1 * cosf(f1) + k0 * sinf(f1);
    const size_t ob = ((size_t)h * S_LEN + s) * HD + d;
    knew[ob] = k0r;       knew[ob + 64] = k1r;
    vnew[ob] = v0;        vnew[ob + 64] = v1;
    kbf[ob]  = f2bf(k0r); kbf[ob + 64]  = f2bf(k1r);
}

__global__ __launch_bounds__(256) void transp_v(const float* __restrict__ qkv,
                                                unsigned short* __restrict__ vT)
{
    __shared__ unsigned short T[64][72];
    const int s0 = blockIdx.x * 64;
    const int dt = blockIdx.y & 1;
    const int h  = blockIdx.y >> 1;
    const int d0 = dt * 64;
    const int tid = threadIdx.x;
    #pragma unroll
    for (int c = 0; c < 4; ++c) {
        const int i = tid + c * 256;
        const int r  = i >> 4;
        const int cc = (i & 15) * 4;
        const float4 v = *(const float4*)(qkv + (size_t)(s0 + r) * NQKV + 5120 + h * HD + d0 + cc);
        T[r][cc + 0] = f2bf(v.x); T[r][cc + 1] = f2bf(v.y);
        T[r][cc + 2] = f2bf(v.z); T[r][cc + 3] = f2bf(v.w);
    }
    __syncthreads();
    #pragma unroll
    for (int c = 0; c < 2; ++c) {
        const int i = tid + c * 256;
        const int dr = i >> 3;
        const int sc = (i & 7) * 8;
        u16x8 o;
        #pragma unroll
        for (int j = 0; j < 8; ++j) o[j] = T[sc + j][dr];
        *(u16x8*)(vT + ((size_t)(h * HD + d0 + dr)) * S_LEN + s0 + sc) = o;
    }
}

// ---------------------------------------------------------------------------
// MFMA flash attention v2 (unchanged from round 3).
// ---------------------------------------------------------------------------
__global__ __launch_bounds__(256) void flash_bf16(const unsigned short* __restrict__ Qbf,
                                                  const unsigned short* __restrict__ Kbf,
                                                  const unsigned short* __restrict__ VbfT,
                                                  unsigned short* __restrict__ Obf)
{
    __shared__ __align__(16) unsigned short Ks[2][64 * 128];
    __shared__ __align__(16) unsigned short Vs[2][128 * 64];
    __shared__ __align__(16) unsigned short Ps[4][16 * 64];

    const int h  = blockIdx.x;
    const int yq = blockIdx.y;
    const int qt = (yq & 1) ? (31 - (yq >> 1)) : (yq >> 1);
    const int hkv = h >> 2;
    const int tid = threadIdx.x;
    const int lane = tid & 63;
    const int w = tid >> 6;
    const int l15 = lane & 15;
    const int l4  = lane >> 4;
    const int ldsWaveBase = (tid & 192) * 16;

    const char* Kg = (const char*)Kbf + (size_t)hkv * S_LEN * HD * 2;
    const char* Vg = (const char*)VbfT + (size_t)hkv * HD * S_LEN * 2;

    bf16x8 qf[4];
    {
        const char* Qg = (const char*)Qbf + ((size_t)h * S_LEN + qt * 64 + w * 16 + l15) * 256;
        #pragma unroll
        for (int kb = 0; kb < 4; ++kb)
            qf[kb] = *(const bf16x8*)(Qg + kb * 64 + l4 * 16);
    }

    auto STAGE = [&](int buf, int kt) {
        #pragma unroll
        for (int c = 0; c < 4; ++c) {
            const int i = tid + c * 256;
            const int kr = i >> 4;
            const int cc = (i & 15) ^ (kr & 7);
            gload16(Kg + (size_t)(kt * 64 + kr) * 256 + cc * 16,
                    (char*)Ks[buf] + ldsWaveBase + c * 4096);
        }
        #pragma unroll
        for (int c = 0; c < 4; ++c) {
            const int i = tid + c * 256;
            const int dr = i >> 3;
            const int cc = (i & 7) ^ (dr & 7);
            gload16(Vg + (size_t)dr * (S_LEN * 2) + (size_t)kt * 128 + cc * 16,
                    (char*)Vs[buf] + ldsWaveBase + c * 4096);
        }
    };

    f32x4 accO[8];
    #pragma unroll
    for (int n = 0; n < 8; ++n) accO[n] = (f32x4){0.f, 0.f, 0.f, 0.f};
    float m_i[4] = {-3e38f, -3e38f, -3e38f, -3e38f};
    float l_i[4] = {0.f, 0.f, 0.f, 0.f};

    STAGE(0, 0);
    __syncthreads();

    for (int kt = 0; kt <= qt; ++kt) {
        const int cbuf = kt & 1;
        if (kt < qt) STAGE(cbuf ^ 1, kt + 1);

        f32x4 sacc[4];
        #pragma unroll
        for (int n = 0; n < 4; ++n) sacc[n] = (f32x4){0.f, 0.f, 0.f, 0.f};
        __builtin_amdgcn_s_setprio(1);
        #pragma unroll
        for (int kb = 0; kb < 4; ++kb) {
            #pragma unroll
            for (int n = 0; n < 4; ++n) {
                const int krow = n * 16 + l15;
                const bf16x8 bk = *(const bf16x8*)((const char*)Ks[cbuf] + krow * 256 +
                                     ((kb * 64 + l4 * 16) ^ ((krow & 7) << 4)));
                sacc[n] = __builtin_amdgcn_mfma_f32_16x16x32_bf16(qf[kb], bk, sacc[n], 0, 0, 0);
            }
        }
        __builtin_amdgcn_s_setprio(0);

        float s0v[4], s1v[4], s2v[4], s3v[4], pm[4];
        #pragma unroll
        for (int reg = 0; reg < 4; ++reg) {
            float s0 = sacc[0][reg], s1 = sacc[1][reg];
            float s2 = sacc[2][reg], s3 = sacc[3][reg];
            if (kt == qt) {
                const int qglob = qt * 64 + w * 16 + l4 * 4 + reg;
                const int kvb = kt * 64 + l15;
                if (kvb +  0 > qglob) s0 = -3e38f;
                if (kvb + 16 > qglob) s1 = -3e38f;
                if (kvb + 32 > qglob) s2 = -3e38f;
                if (kvb + 48 > qglob) s3 = -3e38f;
            }
            float rmax = fmaxf(fmaxf(s0, s1), fmaxf(s2, s3));
            rmax = fmaxf(rmax, __shfl_xor(rmax, 1));
            rmax = fmaxf(rmax, __shfl_xor(rmax, 2));
            rmax = fmaxf(rmax, __shfl_xor(rmax, 4));
            rmax = fmaxf(rmax, __shfl_xor(rmax, 8));
            pm[reg] = rmax;
            s0v[reg] = s0; s1v[reg] = s1; s2v[reg] = s2; s3v[reg] = s3;
        }

        const bool grew = (pm[0] > m_i[0] + 8.f) || (pm[1] > m_i[1] + 8.f) ||
                          (pm[2] > m_i[2] + 8.f) || (pm[3] > m_i[3] + 8.f);
        if (__any(grew)) {
            #pragma unroll
            for (int reg = 0; reg < 4; ++reg) {
                const float mnew = fmaxf(m_i[reg], pm[reg]);
                const float csc = exp2f(m_i[reg] - mnew);
                l_i[reg] *= csc;
                m_i[reg] = mnew;
                #pragma unroll
                for (int n = 0; n < 8; ++n) accO[n][reg] *= csc;
            }
        }

        unsigned short* Pw = &Ps[w][0];
        #pragma unroll
        for (int reg = 0; reg < 4; ++reg) {
            const float p0 = exp2f(s0v[reg] - m_i[reg]);
            const float p1 = exp2f(s1v[reg] - m_i[reg]);
            const float p2 = exp2f(s2v[reg] - m_i[reg]);
            const float p3 = exp2f(s3v[reg] - m_i[reg]);
            const int rl = l4 * 4 + reg;
            const int sf = (rl & 7) << 4;
            *(unsigned short*)((char*)Pw + rl * 128 + (( 0 + l15 * 2) ^ sf)) = f2bf(p0);
            *(unsigned short*)((char*)Pw + rl * 128 + ((32 + l15 * 2) ^ sf)) = f2bf(p1);
            *(unsigned short*)((char*)Pw + rl * 128 + ((64 + l15 * 2) ^ sf)) = f2bf(p2);
            *(unsigned short*)((char*)Pw + rl * 128 + ((96 + l15 * 2) ^ sf)) = f2bf(p3);
            float rsum = p0 + p1 + p2 + p3;
            rsum += __shfl_xor(rsum, 1);
            rsum += __shfl_xor(rsum, 2);
            rsum += __shfl_xor(rsum, 4);
            rsum += __shfl_xor(rsum, 8);
            l_i[reg] += rsum;
        }

        const char* Pwb = (const char*)Pw;
        __builtin_amdgcn_s_setprio(1);
        #pragma unroll
        for (int kb = 0; kb < 2; ++kb) {
            const bf16x8 pa = *(const bf16x8*)(Pwb + l15 * 128 +
                                 ((kb * 64 + l4 * 16) ^ ((l15 & 7) << 4)));
            #pragma unroll
            for (int n = 0; n < 8; ++n) {
                const int vrow = n * 16 + l15;
                const bf16x8 vb = *(const bf16x8*)((const char*)Vs[cbuf] + vrow * 128 +
                                     ((kb * 64 + l4 * 16) ^ ((vrow & 7) << 4)));
                accO[n] = __builtin_amdgcn_mfma_f32_16x16x32_bf16(pa, vb, accO[n], 0, 0, 0);
            }
        }
        __builtin_amdgcn_s_setprio(0);

        __syncthreads();
    }

    float invl[4];
    #pragma unroll
    for (int reg = 0; reg < 4; ++reg) invl[reg] = 1.f / l_i[reg];
    #pragma unroll
    for (int n = 0; n < 8; ++n)
        #pragma unroll
        for (int reg = 0; reg < 4; ++reg) {
            const int row = qt * 64 + w * 16 + l4 * 4 + reg;
            Obf[(size_t)row * DQ + h * HD + n * 16 + l15] = f2bf(accO[n][reg] * invl[reg]);
        }
}

// ---------------------------------------------------------------------------
// d_out (fp32): [ out: S*DQ | k_new | v_new ]
// d_ws: x_bf 16MB @0 (attn_bf aliases) | wqkv_bf 48MB @16 (wo_bf aliases)
//       qkv_f32 48MB @64 | q_bf 16MB @112 | k_bf 4MB @128 | vT_bf 4MB @132
// ---------------------------------------------------------------------------
extern "C" void kernel_launch(void* const* d_in, const int* in_sizes, int n_in,
                              void* d_out, int out_size, void* d_ws, size_t ws_size,
                              hipStream_t stream)
{
    const float* x    = (const float*)d_in[0];
    const float* freq = (const float*)d_in[1];
    const float* wq   = (const float*)d_in[2];
    const float* wk   = (const float*)d_in[3];
    const float* wv   = (const float*)d_in[4];
    const float* wo   = (const float*)d_in[5];

    float* out  = (float*)d_out;
    float* knew = out + (size_t)S_LEN * DQ;
    float* vnew = knew + (size_t)NHKV * S_LEN * HD;

    char* ws = (char*)d_ws;
    unsigned short* x_bf    = (unsigned short*)(ws);
    unsigned short* attn_bf = (unsigned short*)(ws);               // aliases x_bf
    unsigned short* wqkv_bf = (unsigned short*)(ws + (16u << 20));
    unsigned short* wo_bf   = (unsigned short*)(ws + (16u << 20)); // aliases wqkv
    float*          qkv_f32 = (float*)(ws + (64u << 20));
    unsigned short* q_bf    = (unsigned short*)(ws + (112u << 20));
    unsigned short* k_bf    = (unsigned short*)(ws + (128u << 20));
    unsigned short* vT_bf   = (unsigned short*)(ws + (132u << 20));

    const dim3 blk(256);

    cvt_bf16<<<2048, blk, 0, stream>>>(x,  x_bf, S_LEN * DMODEL / 8);
    cvt_bf16<<<2048, blk, 0, stream>>>(wq, wqkv_bf, DQ * DMODEL / 8);
    cvt_bf16<<<1024, blk, 0, stream>>>(wk, wqkv_bf + (size_t)DQ * DMODEL, DKV * DMODEL / 8);
    cvt_bf16<<<1024, blk, 0, stream>>>(wv, wqkv_bf + (size_t)(DQ + DKV) * DMODEL, DKV * DMODEL / 8);

    // fused QKV projection: [2048,6144] = x @ [wq;wk;wv]^T  (256sq 8-phase)
    gemm_bf16_256<<<dim3(NQKV / GBN, S_LEN / GBM), dim3(512), 0, stream>>>(
        x_bf, wqkv_bf, qkv_f32, S_LEN, NQKV, DMODEL);

    cvt_bf16<<<2048, blk, 0, stream>>>(wo, wo_bf, DMODEL * DQ / 8);

    rope_q<<<NHQ * S_LEN * 64 / 256, blk, 0, stream>>>(qkv_f32, freq, q_bf);
    rope_kv<<<NHKV * S_LEN * 64 / 256, blk, 0, stream>>>(qkv_f32, freq, knew, vnew, k_bf);
    transp_v<<<dim3(S_LEN / 64, 2 * NHKV), blk, 0, stream>>>(qkv_f32, vT_bf);

    flash_bf16<<<dim3(NHQ, S_LEN / 64), blk, 0, stream>>>(q_bf, k_bf, vT_bf, attn_bf);

    // output projection: out = attn @ wo^T  (128sq 2-barrier — in-run control)
    gemm_bf16<<<dim3(DMODEL / BBN, S_LEN / BBM), blk, 0, stream>>>(attn_bf, wo_bf, out, S_LEN, DMODEL, DMODEL);
}